// Round 10
// baseline (652.000 us; speedup 1.0000x reference)
//
#include <hip/hip_runtime.h>
#include <hip/hip_bf16.h>

#define NN 100000
#define NE 3200000
#define NB 512
#define DIN 500
#define DH 64
#define HIDN 200
#define NCLS 80

#define NBUK 256
#define NPB 391
#define EPB 16384
#define NBLK_E ((NE + EPB - 1) / EPB)   // 196

typedef __attribute__((ext_vector_type(8))) short bf16x8;
typedef __attribute__((ext_vector_type(4))) float f32x4;

__device__ __forceinline__ short f2bf(float f) {
    union { float f; unsigned u; } v; v.f = f;
    unsigned r = v.u + 0x7FFF + ((v.u >> 16) & 1);   // RNE
    return (short)(r >> 16);
}
__device__ __forceinline__ float bf2f(short s) {
    union { unsigned u; float f; } v; v.u = ((unsigned)(unsigned short)s) << 16;
    return v.f;
}

// ---------- CSR pass A: per-block bucket histogram ----------
__global__ void bukhist_kernel(const int* __restrict__ dst, int* __restrict__ block_hist) {
    __shared__ int h[NBUK];
    for (int i = threadIdx.x; i < NBUK; i += 256) h[i] = 0;
    __syncthreads();
    int base = blockIdx.x * EPB;
    int end = min(base + EPB, NE);
    for (int e = base + threadIdx.x; e < end; e += 256)
        atomicAdd(&h[dst[e] / NPB], 1);
    __syncthreads();
    for (int i = threadIdx.x; i < NBUK; i += 256)
        block_hist[blockIdx.x * NBUK + i] = h[i];
}

// ---------- CSR pass B ----------
__global__ void bukoff_kernel(int* __restrict__ block_hist, int* __restrict__ buk_base) {
    __shared__ int tot[NBUK];
    __shared__ int sc[NBUK];
    int b = threadIdx.x;
    int s = 0;
    for (int i = 0; i < NBLK_E; ++i) s += block_hist[i * NBUK + b];
    tot[b] = s; sc[b] = s;
    __syncthreads();
    for (int o = 1; o < NBUK; o <<= 1) {
        int t = (b >= o) ? sc[b - o] : 0;
        __syncthreads();
        sc[b] += t;
        __syncthreads();
    }
    int excl = sc[b] - tot[b];
    buk_base[b] = excl;
    if (b == NBUK - 1) buk_base[NBUK] = excl + tot[b];
    int run = excl;
    for (int i = 0; i < NBLK_E; ++i) {
        int idx = i * NBUK + b;
        int v = block_hist[idx];
        block_hist[idx] = run;
        run += v;
    }
}

// ---------- CSR pass C ----------
__global__ void bukscat_kernel(const int* __restrict__ src, const int* __restrict__ dst,
                               const int* __restrict__ block_hist, int* __restrict__ bpack) {
    __shared__ int cur[NBUK];
    for (int i = threadIdx.x; i < NBUK; i += 256)
        cur[i] = block_hist[blockIdx.x * NBUK + i];
    __syncthreads();
    int base = blockIdx.x * EPB;
    int end = min(base + EPB, NE);
    for (int e = base + threadIdx.x; e < end; e += 256) {
        int d = dst[e];
        int bk = d / NPB;
        int p = atomicAdd(&cur[bk], 1);
        bpack[p] = (src[e] << 9) | (d - bk * NPB);
    }
}

// ---------- CSR pass D ----------
__global__ void bukfin_kernel(const int* __restrict__ buk_base, const int* __restrict__ bpack,
                              int* __restrict__ row_ptr, float* __restrict__ invdeg,
                              int* __restrict__ csr_src) {
    __shared__ int cnt[NPB];
    __shared__ int cbase[NPB];
    int bk = blockIdx.x;
    int n0 = bk * NPB;
    int nloc = min(n0 + NPB, NN) - n0;
    for (int i = threadIdx.x; i < nloc; i += 256) cnt[i] = 0;
    __syncthreads();
    int beg = buk_base[bk], end = buk_base[bk + 1];
    for (int p = beg + threadIdx.x; p < end; p += 256)
        atomicAdd(&cnt[bpack[p] & 511], 1);
    __syncthreads();
    if (threadIdx.x == 0) {
        int run = beg;
        for (int i = 0; i < nloc; ++i) { int v = cnt[i]; cbase[i] = run; run += v; }
    }
    __syncthreads();
    for (int i = threadIdx.x; i < nloc; i += 256) {
        row_ptr[n0 + i] = cbase[i];
        invdeg[n0 + i] = 1.0f / fmaxf((float)cnt[i], 1.0f);
        cnt[i] = cbase[i];
    }
    if (bk == NBUK - 1 && threadIdx.x == 0) row_ptr[NN] = end;
    __syncthreads();
    for (int p = beg + threadIdx.x; p < end; p += 256) {
        int v = bpack[p];
        int q = atomicAdd(&cnt[v & 511], 1);
        csr_src[q] = v >> 9;
    }
}

// ---------- W prep: Wb[col][k] bf16, zero-pad k>=K ----------
__global__ void wprep_kernel(const float* __restrict__ Wl, const float* __restrict__ Wr,
                             short* __restrict__ Wb, int K, int KP) {
    int id = blockIdx.x * blockDim.x + threadIdx.x;
    if (id >= 128 * KP) return;
    int col = id / KP, k = id - col * KP;
    float v = 0.f;
    if (k < K) v = (col < 64) ? Wl[(size_t)k * 64 + col] : Wr[(size_t)k * 64 + (col - 64)];
    Wb[(size_t)col * KP + k] = f2bf(v);
}

// ---------- conv1: zero-LDS zero-barrier direct MFMA GEMM, wave = 16 rows x 128 cols ----------
// A: lane (row=l&15, k=(l>>4)*8+i) -> 4 lanes/row read 128B contiguous per K-step (coalesced).
// B: 128 KB bf16, streamed from L2. L1 row-norm: in-wave shfl reduce. No __syncthreads at all.
__launch_bounds__(256)
__global__ void gemm_direct(const float* __restrict__ in, const short* __restrict__ Wb,
                            short* __restrict__ Hl, float* __restrict__ Hr) {
    const int tid = threadIdx.x;
    const int w = tid >> 6, l = tid & 63;
    const int q = l >> 4, r16 = l & 15;
    const int tile0 = blockIdx.x * 64 + w * 16;     // wave's 16-row tile
    const int arow_i = tile0 + r16;
    const bool ok = arow_i < NN;
    const float* arow = in + (size_t)(ok ? arow_i : 0) * DIN + q * 8;

    f32x4 acc[8];
#pragma unroll
    for (int c = 0; c < 8; ++c) acc[c] = (f32x4){0.f, 0.f, 0.f, 0.f};
    float pabs = 0.f;

#pragma unroll
    for (int t = 0; t < 16; ++t) {
        float v[8];
        if (t < 15) {
            const float4 f0 = *(const float4*)(arow + t * 32);
            const float4 f1 = *(const float4*)(arow + t * 32 + 4);
            v[0] = f0.x; v[1] = f0.y; v[2] = f0.z; v[3] = f0.w;
            v[4] = f1.x; v[5] = f1.y; v[6] = f1.z; v[7] = f1.w;
        } else {
#pragma unroll
            for (int i = 0; i < 8; ++i) {
                int gk = t * 32 + q * 8 + i;
                v[i] = (gk < DIN) ? arow[t * 32 + i] : 0.f;
            }
        }
        short sh[8];
#pragma unroll
        for (int i = 0; i < 8; ++i) { pabs += fabsf(v[i]); sh[i] = f2bf(v[i]); }
        bf16x8 a = *(bf16x8*)sh;
#pragma unroll
        for (int c = 0; c < 8; ++c) {
            bf16x8 b = *(const bf16x8*)(Wb + (size_t)(c * 16 + r16) * 512 + t * 32 + q * 8);
            acc[c] = __builtin_amdgcn_mfma_f32_16x16x32_bf16(a, b, acc[c], 0, 0, 0);
        }
    }

    // per-row L1 inverse norm: sum the 4 k-chunk lanes of each row (xor lane bits 4,5)
    pabs += __shfl_xor(pabs, 16, 64);
    pabs += __shfl_xor(pabs, 32, 64);
    float sval = 1.0f / fmaxf(pabs, 1e-12f);       // lane l: s for row (l&15)

#pragma unroll
    for (int rr = 0; rr < 4; ++rr) {
        int lrow = q * 4 + rr;                     // C/D: row=(lane>>4)*4+reg, col=lane&15
        float srow = __shfl(sval, lrow, 64);
        int grow = tile0 + lrow;
        if (grow < NN) {
#pragma unroll
            for (int c = 0; c < 8; ++c) {
                float o = acc[c][rr] * srow;
                if (c < 4) Hl[(size_t)grow * 64 + c * 16 + r16] = f2bf(o);
                else       Hr[(size_t)grow * 64 + (c - 4) * 16 + r16] = o;
            }
        }
    }
}

// ---------- conv2/3: barrier-free MFMA GEMM, K=64, bf16 in ----------
__launch_bounds__(256)
__global__ void gemm64_mfma(const short* __restrict__ ein, const short* __restrict__ Wb,
                            short* __restrict__ Hl, float* __restrict__ Hr) {
    const int tid = threadIdx.x;
    const int row0 = blockIdx.x * 64;
    const int w = tid >> 6, l = tid & 63;
    const int q = l >> 4, r16 = l & 15;
    const int arow = row0 + w * 16 + r16;
    const bool ok = arow < NN;
    const short* ap = ein + (size_t)(ok ? arow : 0) * 64 + q * 8;
    f32x4 acc[8];
#pragma unroll
    for (int c = 0; c < 8; ++c) acc[c] = (f32x4){0.f, 0.f, 0.f, 0.f};
    const bf16x8 z8 = (bf16x8){0, 0, 0, 0, 0, 0, 0, 0};
#pragma unroll
    for (int t = 0; t < 2; ++t) {
        bf16x8 a = ok ? *(const bf16x8*)(ap + t * 32) : z8;
#pragma unroll
        for (int c = 0; c < 8; ++c) {
            bf16x8 b = *(const bf16x8*)(Wb + (size_t)(c * 16 + r16) * 64 + t * 32 + q * 8);
            acc[c] = __builtin_amdgcn_mfma_f32_16x16x32_bf16(a, b, acc[c], 0, 0, 0);
        }
    }
#pragma unroll
    for (int c = 0; c < 8; ++c) {
#pragma unroll
        for (int rr = 0; rr < 4; ++rr) {
            int grow = row0 + w * 16 + q * 4 + rr;
            if (grow < NN) {
                if (c < 4) Hl[(size_t)grow * 64 + c * 16 + r16] = f2bf(acc[c][rr]);
                else       Hr[(size_t)grow * 64 + (c - 4) * 16 + r16] = acc[c][rr];
            }
        }
    }
}

// ---------- CSR gather + fused combine, unroll x4, fp32 Hr; LAST writes fp32 ----------
template<bool LAST>
__launch_bounds__(256, 8)
__global__ void gather_kernel(const int* __restrict__ row_ptr, const int* __restrict__ csr_src,
                              const short* __restrict__ Hl, const float* __restrict__ Hr,
                              const float* __restrict__ invdeg, const float* __restrict__ bl,
                              short* __restrict__ ebf, float* __restrict__ ef32) {
    int node = blockIdx.x * 4 + (threadIdx.x >> 6);
    if (node >= NN) return;
    int lane = threadIdx.x & 63;
    int ng = lane >> 3;          // neighbor sub-group 0..7
    int fl = lane & 7;           // bf16x8 index (8 x 8 = 64 feats)
    int beg = row_ptr[node], end = row_ptr[node + 1];
    float a0[8], a1[8];
#pragma unroll
    for (int j = 0; j < 8; ++j) { a0[j] = 0.f; a1[j] = 0.f; }
    int p = beg + ng;
    for (; p + 24 < end; p += 32) {
        int s0 = csr_src[p];
        int s1 = csr_src[p + 8];
        int s2 = csr_src[p + 16];
        int s3 = csr_src[p + 24];
        bf16x8 v0 = *(const bf16x8*)(Hl + (size_t)s0 * 64 + fl * 8);
        bf16x8 v1 = *(const bf16x8*)(Hl + (size_t)s1 * 64 + fl * 8);
        bf16x8 v2 = *(const bf16x8*)(Hl + (size_t)s2 * 64 + fl * 8);
        bf16x8 v3 = *(const bf16x8*)(Hl + (size_t)s3 * 64 + fl * 8);
#pragma unroll
        for (int j = 0; j < 8; ++j) {
            a0[j] += bf2f(v0[j]) + bf2f(v2[j]);
            a1[j] += bf2f(v1[j]) + bf2f(v3[j]);
        }
    }
    for (; p < end; p += 8) {
        int s0 = csr_src[p];
        bf16x8 v0 = *(const bf16x8*)(Hl + (size_t)s0 * 64 + fl * 8);
#pragma unroll
        for (int j = 0; j < 8; ++j) a0[j] += bf2f(v0[j]);
    }
#pragma unroll
    for (int j = 0; j < 8; ++j) a0[j] += a1[j];
#pragma unroll
    for (int m = 8; m < 64; m <<= 1)
#pragma unroll
        for (int j = 0; j < 8; ++j) a0[j] += __shfl_xor(a0[j], m, 64);
    if (ng == 0) {
        float idg = invdeg[node];
        const float4 h0 = *(const float4*)(Hr + (size_t)node * 64 + fl * 8);
        const float4 h1 = *(const float4*)(Hr + (size_t)node * 64 + fl * 8 + 4);
        float o[8];
        o[0] = a0[0] * idg + bl[fl * 8 + 0] + h0.x;
        o[1] = a0[1] * idg + bl[fl * 8 + 1] + h0.y;
        o[2] = a0[2] * idg + bl[fl * 8 + 2] + h0.z;
        o[3] = a0[3] * idg + bl[fl * 8 + 3] + h0.w;
        o[4] = a0[4] * idg + bl[fl * 8 + 4] + h1.x;
        o[5] = a0[5] * idg + bl[fl * 8 + 5] + h1.y;
        o[6] = a0[6] * idg + bl[fl * 8 + 6] + h1.z;
        o[7] = a0[7] * idg + bl[fl * 8 + 7] + h1.w;
        if (LAST) {
            *(float4*)(ef32 + (size_t)node * 64 + fl * 8)     = make_float4(o[0], o[1], o[2], o[3]);
            *(float4*)(ef32 + (size_t)node * 64 + fl * 8 + 4) = make_float4(o[4], o[5], o[6], o[7]);
        } else {
            short s[8];
#pragma unroll
            for (int j = 0; j < 8; ++j) s[j] = f2bf(o[j]);
            *(bf16x8*)(ebf + (size_t)node * 64 + fl * 8) = *(bf16x8*)s;
        }
    }
}

// ---------- pool: segment starts from sorted batch ----------
__global__ void gseg_kernel(const int* __restrict__ batch, int* __restrict__ gstart) {
    int i = blockIdx.x * blockDim.x + threadIdx.x;
    if (i >= NN) return;
    int bc = batch[i];
    int bp = (i == 0) ? -1 : batch[i - 1];
    for (int b = bp + 1; b <= bc; ++b) gstart[b] = i;
    if (i == NN - 1)
        for (int b = bc + 1; b <= NB; ++b) gstart[b] = NN;
}

// ---------- pool: segmented mean over fp32 e3, no atomics ----------
__launch_bounds__(256)
__global__ void pool_seg(const float* __restrict__ e, const int* __restrict__ gstart,
                         float* __restrict__ c0) {
    __shared__ float part[4][64];
    int b = blockIdx.x;
    int w = threadIdx.x >> 6, lane = threadIdx.x & 63;
    int s = gstart[b], t = gstart[b + 1];
    float acc = 0.f;
    for (int i = s + w; i < t; i += 4) acc += e[(size_t)i * 64 + lane];
    part[w][lane] = acc;
    __syncthreads();
    if (w == 0) {
        float v = part[0][lane] + part[1][lane] + part[2][lane] + part[3][lane];
        c0[b * 64 + lane] = v / fmaxf((float)(t - s), 1.0f);
    }
}

// ---------- MLP head ----------
__global__ void lin_kernel(const float* __restrict__ in, const float* __restrict__ W,
                           const float* __restrict__ bias, float* __restrict__ out,
                           int Kd, int Dout) {
    int id = blockIdx.x * blockDim.x + threadIdx.x;
    if (id >= NB * Dout) return;
    int row = id / Dout, col = id - row * Dout;
    const float* ir = in + (size_t)row * Kd;
    float acc = bias[col];
    for (int k = 0; k < Kd; ++k) acc += ir[k] * W[(size_t)k * Dout + col];
    out[id] = acc;
}

__global__ void bnstats_kernel(const float* __restrict__ c, const float* __restrict__ g,
                               const float* __restrict__ beta, float* __restrict__ sa,
                               float* __restrict__ sb, int Dout) {
    int col = blockIdx.x;
    int tid = threadIdx.x;
    float s = 0.f, sq = 0.f;
    for (int r = tid; r < NB; r += 256) {
        float v = c[(size_t)r * Dout + col];
        s += v; sq += v * v;
    }
    __shared__ float ls[256], lq[256];
    ls[tid] = s; lq[tid] = sq;
    __syncthreads();
    for (int o = 128; o > 0; o >>= 1) {
        if (tid < o) { ls[tid] += ls[tid + o]; lq[tid] += lq[tid + o]; }
        __syncthreads();
    }
    if (tid == 0) {
        float mu = ls[0] / NB;
        float var = lq[0] / NB - mu * mu;
        float a = g[col] * rsqrtf(var + 1e-5f);
        sa[col] = a;
        sb[col] = beta[col] - mu * a;
    }
}

__global__ void bnapply_kernel(const float* __restrict__ c, const float* __restrict__ sa,
                               const float* __restrict__ sb, float* __restrict__ bv, int Dout) {
    int id = blockIdx.x * blockDim.x + threadIdx.x;
    if (id >= NB * Dout) return;
    int col = id % Dout;
    bv[id] = tanhf(c[id] * sa[col] + sb[col]);
}

extern "C" void kernel_launch(void* const* d_in, const int* in_sizes, int n_in,
                              void* d_out, int out_size, void* d_ws, size_t ws_size,
                              hipStream_t stream) {
    const float* x    = (const float*)d_in[0];
    const int* ei     = (const int*)d_in[1];
    const int* src    = ei;
    const int* dst    = ei + NE;
    const int* batch  = (const int*)d_in[2];
    const float* c1Wl = (const float*)d_in[4];
    const float* c1bl = (const float*)d_in[5];
    const float* c1Wr = (const float*)d_in[6];
    const float* c2Wl = (const float*)d_in[7];
    const float* c2bl = (const float*)d_in[8];
    const float* c2Wr = (const float*)d_in[9];
    const float* c3Wl = (const float*)d_in[10];
    const float* c3bl = (const float*)d_in[11];
    const float* c3Wr = (const float*)d_in[12];
    const float* l1W  = (const float*)d_in[13]; const float* l1b = (const float*)d_in[14];
    const float* bn1g = (const float*)d_in[15]; const float* bn1b = (const float*)d_in[16];
    const float* l2W  = (const float*)d_in[17]; const float* l2b = (const float*)d_in[18];
    const float* bn2g = (const float*)d_in[19]; const float* bn2b = (const float*)d_in[20];
    const float* l3W  = (const float*)d_in[21]; const float* l3b = (const float*)d_in[22];
    const float* bn3g = (const float*)d_in[23]; const float* bn3b = (const float*)d_in[24];
    const float* l4W  = (const float*)d_in[25]; const float* l4b = (const float*)d_in[26];
    float* out = (float*)d_out;

    char* wsb = (char*)d_ws;
    short* Hl     = (short*)wsb; wsb += (size_t)NN * 64 * 2;
    float* Hr     = (float*)wsb; wsb += (size_t)NN * 64 * 4;
    short* e      = (short*)wsb; wsb += (size_t)NN * 64 * 2;
    float* e3     = (float*)wsb; wsb += (size_t)NN * 64 * 4;
    float* invdeg = (float*)wsb; wsb += (size_t)NN * 4;
    float* c      = (float*)wsb; wsb += (size_t)NB * HIDN * 4;
    float* bv     = (float*)wsb; wsb += (size_t)NB * HIDN * 4;
    float* sa     = (float*)wsb; wsb += HIDN * 4;
    float* sb     = (float*)wsb; wsb += HIDN * 4;
    short* Wb1    = (short*)wsb; wsb += 128 * 512 * 2;
    short* Wb2    = (short*)wsb; wsb += 128 * 64 * 2;
    short* Wb3    = (short*)wsb; wsb += 128 * 64 * 2;
    int* row_ptr  = (int*)wsb;   wsb += (size_t)(NN + 1) * 4;
    int* csr_src  = (int*)wsb;   wsb += (size_t)NE * 4;
    int* buk_base = (int*)wsb;   wsb += (NBUK + 1) * 4;
    int* gstart   = (int*)wsb;   wsb += (NB + 1) * 4;
    // scratch aliased into buffers dead during CSR build:
    int* bpack      = (int*)Hl;  // NE ints = 12.8 MB == sizeof(Hl)
    int* block_hist = (int*)e;   // 200 KB

    // ---- CSR build: bucketed counting sort ----
    bukhist_kernel<<<NBLK_E, 256, 0, stream>>>(dst, block_hist);
    bukoff_kernel<<<1, NBUK, 0, stream>>>(block_hist, buk_base);
    bukscat_kernel<<<NBLK_E, 256, 0, stream>>>(src, dst, block_hist, bpack);
    bukfin_kernel<<<NBUK, 256, 0, stream>>>(buk_base, bpack, row_ptr, invdeg, csr_src);

    // ---- graph segment table ----
    gseg_kernel<<<(NN + 255) / 256, 256, 0, stream>>>(batch, gstart);

    // ---- weight prep ----
    wprep_kernel<<<(128 * 512 + 255) / 256, 256, 0, stream>>>(c1Wl, c1Wr, Wb1, DIN, 512);
    wprep_kernel<<<(128 * 64 + 255) / 256, 256, 0, stream>>>(c2Wl, c2Wr, Wb2, DH, 64);
    wprep_kernel<<<(128 * 64 + 255) / 256, 256, 0, stream>>>(c3Wl, c3Wr, Wb3, DH, 64);

    const int GB64 = (NN + 63) / 64;
    const int GGB  = (NN + 3) / 4;

    // conv1
    gemm_direct<<<GB64, 256, 0, stream>>>(x, Wb1, Hl, Hr);
    gather_kernel<false><<<GGB, 256, 0, stream>>>(row_ptr, csr_src, Hl, Hr, invdeg, c1bl, e, e3);
    // conv2
    gemm64_mfma<<<GB64, 256, 0, stream>>>(e, Wb2, Hl, Hr);
    gather_kernel<false><<<GGB, 256, 0, stream>>>(row_ptr, csr_src, Hl, Hr, invdeg, c2bl, e, e3);
    // conv3
    gemm64_mfma<<<GB64, 256, 0, stream>>>(e, Wb3, Hl, Hr);
    gather_kernel<true><<<GGB, 256, 0, stream>>>(row_ptr, csr_src, Hl, Hr, invdeg, c3bl, e, e3);

    // pool -> bv holds c0 [512,64] fp32
    pool_seg<<<NB, 256, 0, stream>>>(e3, gstart, bv);

    // head
    lin_kernel<<<(NB * 200 + 255) / 256, 256, 0, stream>>>(bv, l1W, l1b, c, 64, 200);
    bnstats_kernel<<<200, 256, 0, stream>>>(c, bn1g, bn1b, sa, sb, 200);
    bnapply_kernel<<<(NB * 200 + 255) / 256, 256, 0, stream>>>(c, sa, sb, bv, 200);

    lin_kernel<<<(NB * 100 + 255) / 256, 256, 0, stream>>>(bv, l2W, l2b, c, 200, 100);
    bnstats_kernel<<<100, 256, 0, stream>>>(c, bn2g, bn2b, sa, sb, 100);
    bnapply_kernel<<<(NB * 100 + 255) / 256, 256, 0, stream>>>(c, sa, sb, bv, 100);

    lin_kernel<<<(NB * 100 + 255) / 256, 256, 0, stream>>>(bv, l3W, l3b, c, 100, 100);
    bnstats_kernel<<<100, 256, 0, stream>>>(c, bn3g, bn3b, sa, sb, 100);
    bnapply_kernel<<<(NB * 100 + 255) / 256, 256, 0, stream>>>(c, sa, sb, bv, 100);

    lin_kernel<<<(NB * 80 + 255) / 256, 256, 0, stream>>>(bv, l4W, l4b, out, 100, 80);
}

// Round 11
// 595.245 us; speedup vs baseline: 1.0953x; 1.0953x over previous
//
#include <hip/hip_runtime.h>
#include <hip/hip_bf16.h>

#define NN 100000
#define NE 3200000
#define NB 512
#define DIN 500
#define DH 64
#define HIDN 200
#define NCLS 80

#define NBUK 256
#define NPB 391
#define EPB 16384
#define NBLK_E ((NE + EPB - 1) / EPB)   // 196

typedef __attribute__((ext_vector_type(8))) short bf16x8;
typedef __attribute__((ext_vector_type(4))) float f32x4;

__device__ __forceinline__ short f2bf(float f) {
    union { float f; unsigned u; } v; v.f = f;
    unsigned r = v.u + 0x7FFF + ((v.u >> 16) & 1);   // RNE
    return (short)(r >> 16);
}
__device__ __forceinline__ float bf2f(short s) {
    union { unsigned u; float f; } v; v.u = ((unsigned)(unsigned short)s) << 16;
    return v.f;
}

// ---------- CSR pass A: per-block bucket histogram ----------
__global__ void bukhist_kernel(const int* __restrict__ dst, int* __restrict__ block_hist) {
    __shared__ int h[NBUK];
    for (int i = threadIdx.x; i < NBUK; i += 256) h[i] = 0;
    __syncthreads();
    int base = blockIdx.x * EPB;
    int end = min(base + EPB, NE);
    for (int e = base + threadIdx.x; e < end; e += 256)
        atomicAdd(&h[dst[e] / NPB], 1);
    __syncthreads();
    for (int i = threadIdx.x; i < NBUK; i += 256)
        block_hist[blockIdx.x * NBUK + i] = h[i];
}

// ---------- CSR pass B ----------
__global__ void bukoff_kernel(int* __restrict__ block_hist, int* __restrict__ buk_base) {
    __shared__ int tot[NBUK];
    __shared__ int sc[NBUK];
    int b = threadIdx.x;
    int s = 0;
    for (int i = 0; i < NBLK_E; ++i) s += block_hist[i * NBUK + b];
    tot[b] = s; sc[b] = s;
    __syncthreads();
    for (int o = 1; o < NBUK; o <<= 1) {
        int t = (b >= o) ? sc[b - o] : 0;
        __syncthreads();
        sc[b] += t;
        __syncthreads();
    }
    int excl = sc[b] - tot[b];
    buk_base[b] = excl;
    if (b == NBUK - 1) buk_base[NBUK] = excl + tot[b];
    int run = excl;
    for (int i = 0; i < NBLK_E; ++i) {
        int idx = i * NBUK + b;
        int v = block_hist[idx];
        block_hist[idx] = run;
        run += v;
    }
}

// ---------- CSR pass C ----------
__global__ void bukscat_kernel(const int* __restrict__ src, const int* __restrict__ dst,
                               const int* __restrict__ block_hist, int* __restrict__ bpack) {
    __shared__ int cur[NBUK];
    for (int i = threadIdx.x; i < NBUK; i += 256)
        cur[i] = block_hist[blockIdx.x * NBUK + i];
    __syncthreads();
    int base = blockIdx.x * EPB;
    int end = min(base + EPB, NE);
    for (int e = base + threadIdx.x; e < end; e += 256) {
        int d = dst[e];
        int bk = d / NPB;
        int p = atomicAdd(&cur[bk], 1);
        bpack[p] = (src[e] << 9) | (d - bk * NPB);
    }
}

// ---------- CSR pass D ----------
__global__ void bukfin_kernel(const int* __restrict__ buk_base, const int* __restrict__ bpack,
                              int* __restrict__ row_ptr, float* __restrict__ invdeg,
                              int* __restrict__ csr_src) {
    __shared__ int cnt[NPB];
    __shared__ int cbase[NPB];
    int bk = blockIdx.x;
    int n0 = bk * NPB;
    int nloc = min(n0 + NPB, NN) - n0;
    for (int i = threadIdx.x; i < nloc; i += 256) cnt[i] = 0;
    __syncthreads();
    int beg = buk_base[bk], end = buk_base[bk + 1];
    for (int p = beg + threadIdx.x; p < end; p += 256)
        atomicAdd(&cnt[bpack[p] & 511], 1);
    __syncthreads();
    if (threadIdx.x == 0) {
        int run = beg;
        for (int i = 0; i < nloc; ++i) { int v = cnt[i]; cbase[i] = run; run += v; }
    }
    __syncthreads();
    for (int i = threadIdx.x; i < nloc; i += 256) {
        row_ptr[n0 + i] = cbase[i];
        invdeg[n0 + i] = 1.0f / fmaxf((float)cnt[i], 1.0f);
        cnt[i] = cbase[i];
    }
    if (bk == NBUK - 1 && threadIdx.x == 0) row_ptr[NN] = end;
    __syncthreads();
    for (int p = beg + threadIdx.x; p < end; p += 256) {
        int v = bpack[p];
        int q = atomicAdd(&cnt[v & 511], 1);
        csr_src[q] = v >> 9;
    }
}

// ---------- W prep: Wb[col][k] bf16, zero-pad k>=K ----------
__global__ void wprep_kernel(const float* __restrict__ Wl, const float* __restrict__ Wr,
                             short* __restrict__ Wb, int K, int KP) {
    int id = blockIdx.x * blockDim.x + threadIdx.x;
    if (id >= 128 * KP) return;
    int col = id / KP, k = id - col * KP;
    float v = 0.f;
    if (k < K) v = (col < 64) ? Wl[(size_t)k * 64 + col] : Wr[(size_t)k * 64 + (col - 64)];
    Wb[(size_t)col * KP + k] = f2bf(v);
}

// ---------- conv1: hybrid MFMA GEMM. A: global->reg direct (2-step prefetch, no LDS).
// B: double-buffered LDS (20 KB). One barrier per K-step gates only B. ----------
__launch_bounds__(256)
__global__ void gemm_hyb(const float* __restrict__ in, const short* __restrict__ Wb,
                         short* __restrict__ Hl, float* __restrict__ Hr) {
    __shared__ short B_lds[2][128][40];
    const int tid = threadIdx.x;
    const int w = tid >> 6, l = tid & 63;
    const int q = l >> 4, r16 = l & 15;
    const int tile0 = blockIdx.x * 64 + w * 16;
    const int arow_i = tile0 + r16;
    const bool ok = arow_i < NN;
    const float* arow = in + (size_t)(ok ? arow_i : 0) * DIN + q * 8;
    // B staging: 256 threads cover 128 cols x 32 k per step
    const int sb_col = tid >> 1;
    const int sb_kh  = (tid & 1) * 16;
    const short* bsrc = Wb + (size_t)sb_col * 512 + sb_kh;

    f32x4 acc[8];
#pragma unroll
    for (int c = 0; c < 8; ++c) acc[c] = (f32x4){0.f, 0.f, 0.f, 0.f};
    float pabs = 0.f;
    float va0[8], va1[8];
    bf16x8 vb00, vb01, vb10, vb11;

#define ISSUE(T, S) do { \
    if ((T) < 15) { \
        const float4 f0 = *(const float4*)(arow + (T) * 32); \
        const float4 f1 = *(const float4*)(arow + (T) * 32 + 4); \
        va##S[0] = f0.x; va##S[1] = f0.y; va##S[2] = f0.z; va##S[3] = f0.w; \
        va##S[4] = f1.x; va##S[5] = f1.y; va##S[6] = f1.z; va##S[7] = f1.w; \
    } else { \
        _Pragma("unroll") \
        for (int i = 0; i < 8; ++i) { \
            int gk = (T) * 32 + q * 8 + i; \
            va##S[i] = (gk < DIN) ? arow[(T) * 32 + i] : 0.f; \
        } \
    } \
    vb##S##0 = *(const bf16x8*)(bsrc + (T) * 32); \
    vb##S##1 = *(const bf16x8*)(bsrc + (T) * 32 + 8); \
} while (0)

#define STAGE_B(BUF, S) do { \
    *(bf16x8*)&B_lds[BUF][sb_col][sb_kh]     = vb##S##0; \
    *(bf16x8*)&B_lds[BUF][sb_col][sb_kh + 8] = vb##S##1; \
} while (0)

#define STEP(T, S) do { \
    short sh[8]; \
    _Pragma("unroll") \
    for (int i = 0; i < 8; ++i) { pabs += fabsf(va##S[i]); sh[i] = f2bf(va##S[i]); } \
    bf16x8 a = *(bf16x8*)sh; \
    if ((T) + 2 < 16) ISSUE((T) + 2, S); \
    _Pragma("unroll") \
    for (int c = 0; c < 8; ++c) { \
        bf16x8 b = *(bf16x8*)&B_lds[(T) & 1][c * 16 + r16][q * 8]; \
        acc[c] = __builtin_amdgcn_mfma_f32_16x16x32_bf16(a, b, acc[c], 0, 0, 0); \
    } \
    if ((T) + 1 < 16) { \
        STAGE_B(((T) + 1) & 1, S##_NEXT); \
        __syncthreads(); \
    } \
} while (0)

    ISSUE(0, 0); ISSUE(1, 1);
    STAGE_B(0, 0);
    __syncthreads();
#define S0_NEXT 1
#define S1_NEXT 0
#pragma unroll
    for (int tt = 0; tt < 8; ++tt) {
        { short sh[8];
#pragma unroll
          for (int i = 0; i < 8; ++i) { pabs += fabsf(va0[i]); sh[i] = f2bf(va0[i]); }
          bf16x8 a = *(bf16x8*)sh;
          if (tt * 2 + 2 < 16) ISSUE(tt * 2 + 2, 0);
#pragma unroll
          for (int c = 0; c < 8; ++c) {
              bf16x8 b = *(bf16x8*)&B_lds[0][c * 16 + r16][q * 8];
              acc[c] = __builtin_amdgcn_mfma_f32_16x16x32_bf16(a, b, acc[c], 0, 0, 0);
          }
          STAGE_B(1, 1);
          __syncthreads();
        }
        { short sh[8];
#pragma unroll
          for (int i = 0; i < 8; ++i) { pabs += fabsf(va1[i]); sh[i] = f2bf(va1[i]); }
          bf16x8 a = *(bf16x8*)sh;
          if (tt * 2 + 3 < 16) ISSUE(tt * 2 + 3, 1);
#pragma unroll
          for (int c = 0; c < 8; ++c) {
              bf16x8 b = *(bf16x8*)&B_lds[1][c * 16 + r16][q * 8];
              acc[c] = __builtin_amdgcn_mfma_f32_16x16x32_bf16(a, b, acc[c], 0, 0, 0);
          }
          if (tt < 7) {
              STAGE_B(0, 0);
              __syncthreads();
          }
        }
    }
#undef ISSUE
#undef STAGE_B
#undef STEP
#undef S0_NEXT
#undef S1_NEXT

    // per-row L1 inverse norm: sum the 4 k-chunk lanes of each row (xor lane bits 4,5)
    pabs += __shfl_xor(pabs, 16, 64);
    pabs += __shfl_xor(pabs, 32, 64);
    float sval = 1.0f / fmaxf(pabs, 1e-12f);       // lane l: scale for row (l&15)

#pragma unroll
    for (int rr = 0; rr < 4; ++rr) {
        int lrow = q * 4 + rr;                     // C/D: row=(lane>>4)*4+reg, col=lane&15
        float srow = __shfl(sval, lrow, 64);
        int grow = tile0 + lrow;
        if (grow < NN) {
#pragma unroll
            for (int c = 0; c < 8; ++c) {
                float o = acc[c][rr] * srow;
                if (c < 4) Hl[(size_t)grow * 64 + c * 16 + r16] = f2bf(o);
                else       Hr[(size_t)grow * 64 + (c - 4) * 16 + r16] = o;
            }
        }
    }
}

// ---------- conv2/3: barrier-free MFMA GEMM, K=64, bf16 in ----------
__launch_bounds__(256)
__global__ void gemm64_mfma(const short* __restrict__ ein, const short* __restrict__ Wb,
                            short* __restrict__ Hl, float* __restrict__ Hr) {
    const int tid = threadIdx.x;
    const int row0 = blockIdx.x * 64;
    const int w = tid >> 6, l = tid & 63;
    const int q = l >> 4, r16 = l & 15;
    const int arow = row0 + w * 16 + r16;
    const bool ok = arow < NN;
    const short* ap = ein + (size_t)(ok ? arow : 0) * 64 + q * 8;
    f32x4 acc[8];
#pragma unroll
    for (int c = 0; c < 8; ++c) acc[c] = (f32x4){0.f, 0.f, 0.f, 0.f};
    const bf16x8 z8 = (bf16x8){0, 0, 0, 0, 0, 0, 0, 0};
#pragma unroll
    for (int t = 0; t < 2; ++t) {
        bf16x8 a = ok ? *(const bf16x8*)(ap + t * 32) : z8;
#pragma unroll
        for (int c = 0; c < 8; ++c) {
            bf16x8 b = *(const bf16x8*)(Wb + (size_t)(c * 16 + r16) * 64 + t * 32 + q * 8);
            acc[c] = __builtin_amdgcn_mfma_f32_16x16x32_bf16(a, b, acc[c], 0, 0, 0);
        }
    }
#pragma unroll
    for (int c = 0; c < 8; ++c) {
#pragma unroll
        for (int rr = 0; rr < 4; ++rr) {
            int grow = row0 + w * 16 + q * 4 + rr;
            if (grow < NN) {
                if (c < 4) Hl[(size_t)grow * 64 + c * 16 + r16] = f2bf(acc[c][rr]);
                else       Hr[(size_t)grow * 64 + (c - 4) * 16 + r16] = acc[c][rr];
            }
        }
    }
}

// ---------- CSR gather + fused combine (round-8 form: unroll x2, plain LB) ----------
template<bool LAST>
__launch_bounds__(256)
__global__ void gather_kernel(const int* __restrict__ row_ptr, const int* __restrict__ csr_src,
                              const short* __restrict__ Hl, const float* __restrict__ Hr,
                              const float* __restrict__ invdeg, const float* __restrict__ bl,
                              short* __restrict__ ebf, float* __restrict__ ef32) {
    int node = blockIdx.x * 4 + (threadIdx.x >> 6);
    if (node >= NN) return;
    int lane = threadIdx.x & 63;
    int ng = lane >> 3;          // neighbor sub-group 0..7
    int fl = lane & 7;           // bf16x8 index (8 x 8 = 64 feats)
    int beg = row_ptr[node], end = row_ptr[node + 1];
    float a0[8], a1[8];
#pragma unroll
    for (int j = 0; j < 8; ++j) { a0[j] = 0.f; a1[j] = 0.f; }
    int p = beg + ng;
    for (; p + 8 < end; p += 16) {
        int s0 = csr_src[p];
        int s1 = csr_src[p + 8];
        bf16x8 v0 = *(const bf16x8*)(Hl + (size_t)s0 * 64 + fl * 8);
        bf16x8 v1 = *(const bf16x8*)(Hl + (size_t)s1 * 64 + fl * 8);
#pragma unroll
        for (int j = 0; j < 8; ++j) { a0[j] += bf2f(v0[j]); a1[j] += bf2f(v1[j]); }
    }
    if (p < end) {
        int s0 = csr_src[p];
        bf16x8 v0 = *(const bf16x8*)(Hl + (size_t)s0 * 64 + fl * 8);
#pragma unroll
        for (int j = 0; j < 8; ++j) a0[j] += bf2f(v0[j]);
    }
#pragma unroll
    for (int j = 0; j < 8; ++j) a0[j] += a1[j];
#pragma unroll
    for (int m = 8; m < 64; m <<= 1)
#pragma unroll
        for (int j = 0; j < 8; ++j) a0[j] += __shfl_xor(a0[j], m, 64);
    if (ng == 0) {
        float idg = invdeg[node];
        const float4 h0 = *(const float4*)(Hr + (size_t)node * 64 + fl * 8);
        const float4 h1 = *(const float4*)(Hr + (size_t)node * 64 + fl * 8 + 4);
        float o[8];
        o[0] = a0[0] * idg + bl[fl * 8 + 0] + h0.x;
        o[1] = a0[1] * idg + bl[fl * 8 + 1] + h0.y;
        o[2] = a0[2] * idg + bl[fl * 8 + 2] + h0.z;
        o[3] = a0[3] * idg + bl[fl * 8 + 3] + h0.w;
        o[4] = a0[4] * idg + bl[fl * 8 + 4] + h1.x;
        o[5] = a0[5] * idg + bl[fl * 8 + 5] + h1.y;
        o[6] = a0[6] * idg + bl[fl * 8 + 6] + h1.z;
        o[7] = a0[7] * idg + bl[fl * 8 + 7] + h1.w;
        if (LAST) {
            *(float4*)(ef32 + (size_t)node * 64 + fl * 8)     = make_float4(o[0], o[1], o[2], o[3]);
            *(float4*)(ef32 + (size_t)node * 64 + fl * 8 + 4) = make_float4(o[4], o[5], o[6], o[7]);
        } else {
            short s[8];
#pragma unroll
            for (int j = 0; j < 8; ++j) s[j] = f2bf(o[j]);
            *(bf16x8*)(ebf + (size_t)node * 64 + fl * 8) = *(bf16x8*)s;
        }
    }
}

// ---------- pool: segment starts from sorted batch ----------
__global__ void gseg_kernel(const int* __restrict__ batch, int* __restrict__ gstart) {
    int i = blockIdx.x * blockDim.x + threadIdx.x;
    if (i >= NN) return;
    int bc = batch[i];
    int bp = (i == 0) ? -1 : batch[i - 1];
    for (int b = bp + 1; b <= bc; ++b) gstart[b] = i;
    if (i == NN - 1)
        for (int b = bc + 1; b <= NB; ++b) gstart[b] = NN;
}

// ---------- pool: segmented mean over fp32 e3, no atomics ----------
__launch_bounds__(256)
__global__ void pool_seg(const float* __restrict__ e, const int* __restrict__ gstart,
                         float* __restrict__ c0) {
    __shared__ float part[4][64];
    int b = blockIdx.x;
    int w = threadIdx.x >> 6, lane = threadIdx.x & 63;
    int s = gstart[b], t = gstart[b + 1];
    float acc = 0.f;
    for (int i = s + w; i < t; i += 4) acc += e[(size_t)i * 64 + lane];
    part[w][lane] = acc;
    __syncthreads();
    if (w == 0) {
        float v = part[0][lane] + part[1][lane] + part[2][lane] + part[3][lane];
        c0[b * 64 + lane] = v / fmaxf((float)(t - s), 1.0f);
    }
}

// ---------- MLP head ----------
__global__ void lin_kernel(const float* __restrict__ in, const float* __restrict__ W,
                           const float* __restrict__ bias, float* __restrict__ out,
                           int Kd, int Dout) {
    int id = blockIdx.x * blockDim.x + threadIdx.x;
    if (id >= NB * Dout) return;
    int row = id / Dout, col = id - row * Dout;
    const float* ir = in + (size_t)row * Kd;
    float acc = bias[col];
    for (int k = 0; k < Kd; ++k) acc += ir[k] * W[(size_t)k * Dout + col];
    out[id] = acc;
}

__global__ void bnstats_kernel(const float* __restrict__ c, const float* __restrict__ g,
                               const float* __restrict__ beta, float* __restrict__ sa,
                               float* __restrict__ sb, int Dout) {
    int col = blockIdx.x;
    int tid = threadIdx.x;
    float s = 0.f, sq = 0.f;
    for (int r = tid; r < NB; r += 256) {
        float v = c[(size_t)r * Dout + col];
        s += v; sq += v * v;
    }
    __shared__ float ls[256], lq[256];
    ls[tid] = s; lq[tid] = sq;
    __syncthreads();
    for (int o = 128; o > 0; o >>= 1) {
        if (tid < o) { ls[tid] += ls[tid + o]; lq[tid] += lq[tid + o]; }
        __syncthreads();
    }
    if (tid == 0) {
        float mu = ls[0] / NB;
        float var = lq[0] / NB - mu * mu;
        float a = g[col] * rsqrtf(var + 1e-5f);
        sa[col] = a;
        sb[col] = beta[col] - mu * a;
    }
}

__global__ void bnapply_kernel(const float* __restrict__ c, const float* __restrict__ sa,
                               const float* __restrict__ sb, float* __restrict__ bv, int Dout) {
    int id = blockIdx.x * blockDim.x + threadIdx.x;
    if (id >= NB * Dout) return;
    int col = id % Dout;
    bv[id] = tanhf(c[id] * sa[col] + sb[col]);
}

extern "C" void kernel_launch(void* const* d_in, const int* in_sizes, int n_in,
                              void* d_out, int out_size, void* d_ws, size_t ws_size,
                              hipStream_t stream) {
    const float* x    = (const float*)d_in[0];
    const int* ei     = (const int*)d_in[1];
    const int* src    = ei;
    const int* dst    = ei + NE;
    const int* batch  = (const int*)d_in[2];
    const float* c1Wl = (const float*)d_in[4];
    const float* c1bl = (const float*)d_in[5];
    const float* c1Wr = (const float*)d_in[6];
    const float* c2Wl = (const float*)d_in[7];
    const float* c2bl = (const float*)d_in[8];
    const float* c2Wr = (const float*)d_in[9];
    const float* c3Wl = (const float*)d_in[10];
    const float* c3bl = (const float*)d_in[11];
    const float* c3Wr = (const float*)d_in[12];
    const float* l1W  = (const float*)d_in[13]; const float* l1b = (const float*)d_in[14];
    const float* bn1g = (const float*)d_in[15]; const float* bn1b = (const float*)d_in[16];
    const float* l2W  = (const float*)d_in[17]; const float* l2b = (const float*)d_in[18];
    const float* bn2g = (const float*)d_in[19]; const float* bn2b = (const float*)d_in[20];
    const float* l3W  = (const float*)d_in[21]; const float* l3b = (const float*)d_in[22];
    const float* bn3g = (const float*)d_in[23]; const float* bn3b = (const float*)d_in[24];
    const float* l4W  = (const float*)d_in[25]; const float* l4b = (const float*)d_in[26];
    float* out = (float*)d_out;

    char* wsb = (char*)d_ws;
    short* Hl     = (short*)wsb; wsb += (size_t)NN * 64 * 2;
    float* Hr     = (float*)wsb; wsb += (size_t)NN * 64 * 4;
    short* e      = (short*)wsb; wsb += (size_t)NN * 64 * 2;
    float* e3     = (float*)wsb; wsb += (size_t)NN * 64 * 4;
    float* invdeg = (float*)wsb; wsb += (size_t)NN * 4;
    float* c      = (float*)wsb; wsb += (size_t)NB * HIDN * 4;
    float* bv     = (float*)wsb; wsb += (size_t)NB * HIDN * 4;
    float* sa     = (float*)wsb; wsb += HIDN * 4;
    float* sb     = (float*)wsb; wsb += HIDN * 4;
    short* Wb1    = (short*)wsb; wsb += 128 * 512 * 2;
    short* Wb2    = (short*)wsb; wsb += 128 * 64 * 2;
    short* Wb3    = (short*)wsb; wsb += 128 * 64 * 2;
    int* row_ptr  = (int*)wsb;   wsb += (size_t)(NN + 1) * 4;
    int* csr_src  = (int*)wsb;   wsb += (size_t)NE * 4;
    int* buk_base = (int*)wsb;   wsb += (NBUK + 1) * 4;
    int* gstart   = (int*)wsb;   wsb += (NB + 1) * 4;
    // scratch aliased into buffers dead during CSR build:
    int* bpack      = (int*)Hl;  // NE ints = 12.8 MB == sizeof(Hl)
    int* block_hist = (int*)e;   // 200 KB

    // ---- CSR build: bucketed counting sort ----
    bukhist_kernel<<<NBLK_E, 256, 0, stream>>>(dst, block_hist);
    bukoff_kernel<<<1, NBUK, 0, stream>>>(block_hist, buk_base);
    bukscat_kernel<<<NBLK_E, 256, 0, stream>>>(src, dst, block_hist, bpack);
    bukfin_kernel<<<NBUK, 256, 0, stream>>>(buk_base, bpack, row_ptr, invdeg, csr_src);

    // ---- graph segment table ----
    gseg_kernel<<<(NN + 255) / 256, 256, 0, stream>>>(batch, gstart);

    // ---- weight prep ----
    wprep_kernel<<<(128 * 512 + 255) / 256, 256, 0, stream>>>(c1Wl, c1Wr, Wb1, DIN, 512);
    wprep_kernel<<<(128 * 64 + 255) / 256, 256, 0, stream>>>(c2Wl, c2Wr, Wb2, DH, 64);
    wprep_kernel<<<(128 * 64 + 255) / 256, 256, 0, stream>>>(c3Wl, c3Wr, Wb3, DH, 64);

    const int GB64 = (NN + 63) / 64;
    const int GGB  = (NN + 3) / 4;

    // conv1
    gemm_hyb<<<GB64, 256, 0, stream>>>(x, Wb1, Hl, Hr);
    gather_kernel<false><<<GGB, 256, 0, stream>>>(row_ptr, csr_src, Hl, Hr, invdeg, c1bl, e, e3);
    // conv2
    gemm64_mfma<<<GB64, 256, 0, stream>>>(e, Wb2, Hl, Hr);
    gather_kernel<false><<<GGB, 256, 0, stream>>>(row_ptr, csr_src, Hl, Hr, invdeg, c2bl, e, e3);
    // conv3
    gemm64_mfma<<<GB64, 256, 0, stream>>>(e, Wb3, Hl, Hr);
    gather_kernel<true><<<GGB, 256, 0, stream>>>(row_ptr, csr_src, Hl, Hr, invdeg, c3bl, e, e3);

    // pool -> bv holds c0 [512,64] fp32
    pool_seg<<<NB, 256, 0, stream>>>(e3, gstart, bv);

    // head
    lin_kernel<<<(NB * 200 + 255) / 256, 256, 0, stream>>>(bv, l1W, l1b, c, 64, 200);
    bnstats_kernel<<<200, 256, 0, stream>>>(c, bn1g, bn1b, sa, sb, 200);
    bnapply_kernel<<<(NB * 200 + 255) / 256, 256, 0, stream>>>(c, sa, sb, bv, 200);

    lin_kernel<<<(NB * 100 + 255) / 256, 256, 0, stream>>>(bv, l2W, l2b, c, 200, 100);
    bnstats_kernel<<<100, 256, 0, stream>>>(c, bn2g, bn2b, sa, sb, 100);
    bnapply_kernel<<<(NB * 100 + 255) / 256, 256, 0, stream>>>(c, sa, sb, bv, 100);

    lin_kernel<<<(NB * 100 + 255) / 256, 256, 0, stream>>>(bv, l3W, l3b, c, 100, 100);
    bnstats_kernel<<<100, 256, 0, stream>>>(c, bn3g, bn3b, sa, sb, 100);
    bnapply_kernel<<<(NB * 100 + 255) / 256, 256, 0, stream>>>(c, sa, sb, bv, 100);

    lin_kernel<<<(NB * 80 + 255) / 256, 256, 0, stream>>>(bv, l4W, l4b, out, 100, 80);
}